// Round 1
// baseline (448.878 us; speedup 1.0000x reference)
//
#include <hip/hip_runtime.h>
#include <hip/hip_bf16.h>
#include <math.h>

typedef unsigned long long u64;
typedef unsigned int u32;

#define C_NUM 80
#define TOPK 1000
#define CAP 4096
#define NB 4096
#define SCORE_THR 0.05f
#define IOU_THR 0.5f

// correctly-rounded-ish f32 exp via double
__device__ __forceinline__ float exp_cr(float x) {
    return (float)exp((double)x);
}

// Exact f32 replication of reference decode + clip (no FMA contraction).
__device__ __forceinline__ void decode_box(const float* __restrict__ anch,
                                           const float* __restrict__ reg,
                                           int a, float fw, float fh, float4* out) {
#pragma clang fp contract(off)
    float a0 = anch[(size_t)a * 4 + 0], a1 = anch[(size_t)a * 4 + 1];
    float a2 = anch[(size_t)a * 4 + 2], a3 = anch[(size_t)a * 4 + 3];
    float d0 = reg[(size_t)a * 4 + 0], d1 = reg[(size_t)a * 4 + 1];
    float d2 = reg[(size_t)a * 4 + 2], d3 = reg[(size_t)a * 4 + 3];
    float w = a2 - a0, h = a3 - a1;
    float cx = a0 + 0.5f * w, cy = a1 + 0.5f * h;
    float dx = d0 * 0.1f, dy = d1 * 0.1f, dw = d2 * 0.2f, dh = d3 * 0.2f;
    float t1 = dx * w; float pcx = cx + t1;
    float t2 = dy * h; float pcy = cy + t2;
    float pw = exp_cr(dw) * w;
    float ph = exp_cr(dh) * h;
    float x1 = pcx - 0.5f * pw, y1 = pcy - 0.5f * ph;
    float x2 = pcx + 0.5f * pw, y2 = pcy + 0.5f * ph;
    x1 = fminf(fmaxf(x1, 0.0f), fw);
    y1 = fminf(fmaxf(y1, 0.0f), fh);
    x2 = fminf(fmaxf(x2, 0.0f), fw);
    y2 = fminf(fmaxf(y2, 0.0f), fh);
    *out = make_float4(x1, y1, x2, y2);
}

// [A][80] -> [80][Apad] coalesced transpose via LDS (stride 81 kills bank conflicts)
__global__ void transpose_kernel(const float* __restrict__ in, float* __restrict__ out,
                                 int A, int Apad) {
    __shared__ float tile[64 * 81];
    int base = blockIdx.x * 64;
    int n = A - base; if (n > 64) n = 64;
    if (n <= 0) return;
    for (int idx = threadIdx.x; idx < n * 80; idx += 256) {
        int r = idx / 80, c = idx - r * 80;
        tile[r * 81 + c] = in[(size_t)base * 80 + idx];
    }
    __syncthreads();
    for (int idx = threadIdx.x; idx < 80 * 64; idx += 256) {
        int c = idx >> 6, r = idx & 63;
        if (r < n) out[(size_t)c * Apad + base + r] = tile[r * 81 + c];
    }
}

// One block per class: histogram -> threshold -> gather -> bitonic sort -> top-1000 decode
__global__ __launch_bounds__(1024)
void select_kernel(const float* __restrict__ cls, const float* __restrict__ scoresT, int useT,
                   const float* __restrict__ anchors, const float* __restrict__ regs,
                   const int* __restrict__ imh, const int* __restrict__ imw,
                   float* __restrict__ candScore, float4* __restrict__ candBox,
                   u64* __restrict__ keepInit, int A, int Apad) {
    __shared__ u64 keys[CAP];              // 32KB; aliased as 8192 u32 for hist+scan
    __shared__ u32 thrBitsS;
    __shared__ int cnt;
    u32* hb = (u32*)keys;
    int c = blockIdx.x, tid = threadIdx.x;

    for (int i = tid; i < NB; i += 1024) hb[i] = 0;
    if (tid == 0) { thrBitsS = 0u; cnt = 0; }
    __syncthreads();

    // histogram of top bits (monotonic for positive floats); bucket width 2^-12 rel in [0.5,1)
    for (int a = tid; a < A; a += 1024) {
        float s = useT ? scoresT[(size_t)c * Apad + a] : cls[(size_t)a * C_NUM + c];
        u32 bits = __float_as_uint(s);
        int b;
        if (bits & 0x80000000u) b = 0;
        else {
            int t = (int)(bits >> 11) - 516096;   // 0x3F000000>>11
            b = t < 0 ? 0 : (t > NB - 1 ? NB - 1 : t);
        }
        atomicAdd(&hb[b], 1u);
    }
    __syncthreads();

    // suffix-sum (Hillis-Steele, ping-pong between hb[0..4095] and hb[4096..8191])
    u32* src = hb; u32* dst = hb + NB;
    for (int d = 1; d < NB; d <<= 1) {
        for (int i = tid; i < NB; i += 1024) {
            u32 v = src[i] + ((i + d < NB) ? src[i + d] : 0u);
            dst[i] = v;
        }
        __syncthreads();
        u32* tmp = src; src = dst; dst = tmp;
    }
    u32* SUF = src;
    for (int i = tid; i < NB; i += 1024) {
        u32 s = SUF[i];
        u32 snext = (i + 1 < NB) ? SUF[i + 1] : 0u;
        if (s >= (u32)TOPK && snext < (u32)TOPK) {
            thrBitsS = (i == 0) ? 0u : (((u32)(i + 516096)) << 11);
        }
    }
    __syncthreads();
    u32 thr = thrBitsS;
    __syncthreads();   // hist region is about to be reused as keys

    // gather all candidates with bits >= thr (positive scores only)
    for (int a = tid; a < A; a += 1024) {
        float s = useT ? scoresT[(size_t)c * Apad + a] : cls[(size_t)a * C_NUM + c];
        u32 bits = __float_as_uint(s);
        if (!(bits & 0x80000000u) && bits >= thr) {
            int p = atomicAdd(&cnt, 1);
            if (p < CAP) keys[p] = ((u64)bits << 32) | (u64)(u32)(~(u32)a);
        }
    }
    __syncthreads();
    int n = cnt; if (n > CAP) n = CAP;
    for (int i = n + tid; i < CAP; i += 1024) keys[i] = 0ull;
    __syncthreads();

    // bitonic sort, descending (key = score_bits:~idx -> score desc, idx asc on ties)
    for (int k = 2; k <= CAP; k <<= 1) {
        for (int j = k >> 1; j > 0; j >>= 1) {
            for (int i = tid; i < CAP; i += 1024) {
                int ixj = i ^ j;
                if (ixj > i) {
                    u64 x = keys[i], y = keys[ixj];
                    bool sw = ((i & k) == 0) ? (x < y) : (x > y);
                    if (sw) { keys[i] = y; keys[ixj] = x; }
                }
            }
            __syncthreads();
        }
    }

    // top-1000: decode + write; build initial keep mask by wave ballot
    float fw = (float)(*imw), fh = (float)(*imh);
    bool valid = false;
    if (tid < TOPK) {
        u64 key = keys[tid];
        u32 bits = (u32)(key >> 32);
        float sc = __uint_as_float(bits);
        int a = (int)(~(u32)key);
        valid = (key != 0ull) && (sc > SCORE_THR);
        float4 bx = make_float4(0.f, 0.f, 0.f, 0.f);
        if (valid) decode_box(anchors, regs, a, fw, fh, &bx);
        candScore[(size_t)c * TOPK + tid] = valid ? sc : 0.0f;
        candBox[(size_t)c * TOPK + tid] = bx;
    }
    u64 m = __ballot(valid);
    if ((tid & 63) == 0) keepInit[c * 16 + (tid >> 6)] = m;
}

// Suppression bit-matrix: sup[c][i][jw] bit j set iff (j>i && iou(i,j)>0.5)
__global__ __launch_bounds__(256)
void iou_kernel(const float4* __restrict__ candBox, u64* __restrict__ supW) {
#pragma clang fp contract(off)
    __shared__ float4 box[TOPK];
    __shared__ float area[TOPK];
    int c = blockIdx.x, chunk = blockIdx.y;
    int tid = threadIdx.x, lane = tid & 63, wave = tid >> 6;
    for (int i = tid; i < TOPK; i += 256) {
        float4 b = candBox[(size_t)c * TOPK + i];
        box[i] = b;
        float ww = fmaxf(b.z - b.x, 0.0f);
        float hh = fmaxf(b.w - b.y, 0.0f);
        area[i] = ww * hh;
    }
    __syncthreads();
    int rowBase = chunk * 200;
    for (int r = wave; r < 200; r += 4) {
        int i = rowBase + r;
        float4 bi = box[i]; float ai = area[i];
        u64* outRow = supW + ((size_t)c * TOPK + i) * 16;
        for (int jw = 0; jw < 16; ++jw) {
            int j = jw * 64 + lane;
            bool sup = false;
            if (j < TOPK && j > i) {
                float4 bj = box[j];
                float ltx = fmaxf(bi.x, bj.x), lty = fmaxf(bi.y, bj.y);
                float rbx = fminf(bi.z, bj.z), rby = fminf(bi.w, bj.w);
                float wj = fmaxf(rbx - ltx, 0.0f), hj = fmaxf(rby - lty, 0.0f);
                float inter = wj * hj;
                float uni = (ai + area[j]) - inter;
                float iou = inter / fmaxf(uni, 1e-8f);
                sup = iou > IOU_THR;
            }
            u64 mm = __ballot(sup);
            if (lane == 0) outRow[jw] = mm;
        }
    }
}

// One wave per class: sequential greedy pass over precomputed sup rows,
// 8-deep register pipeline hides the row-load latency.
__global__ __launch_bounds__(64)
void nms_seq_kernel(const u64* __restrict__ supW, const u64* __restrict__ keepInit,
                    u64* __restrict__ keepFinal) {
    int c = blockIdx.x, lane = threadIdx.x;
    const u64* rows = supW + (size_t)c * TOPK * 16;
    u64 kw = (lane < 16) ? keepInit[c * 16 + lane] : 0ull;
    u64 buf[8];
#pragma unroll
    for (int u = 0; u < 8; ++u)
        buf[u] = (lane < 16) ? rows[(size_t)u * 16 + lane] : 0ull;
    for (int i0 = 0; i0 < TOPK; i0 += 8) {
#pragma unroll
        for (int u = 0; u < 8; ++u) {
            int i = i0 + u;
            u64 word = __shfl(kw, i >> 6);
            if ((word >> (i & 63)) & 1ull) kw &= ~buf[u];
            int nx = i + 8;
            buf[u] = (nx < TOPK && lane < 16) ? rows[(size_t)nx * 16 + lane] : 0ull;
        }
    }
    if (lane < 16) keepFinal[c * 16 + lane] = kw;
}

__global__ void output_kernel(const float* __restrict__ candScore,
                              const float4* __restrict__ candBox,
                              const u64* __restrict__ keepFinal,
                              float* __restrict__ out) {
    int g = blockIdx.x * 256 + threadIdx.x;
    if (g >= C_NUM * TOPK) return;
    int c = g / TOPK, k = g - c * TOPK;
    bool keep = (keepFinal[c * 16 + (k >> 6)] >> (k & 63)) & 1ull;
    out[g] = keep ? candScore[g] : 0.0f;
    out[C_NUM * TOPK + g] = keep ? (float)c : -1.0f;
    float4 b = keep ? candBox[g] : make_float4(0.f, 0.f, 0.f, 0.f);
    ((float4*)(out + 2 * C_NUM * TOPK))[g] = b;
}

extern "C" void kernel_launch(void* const* d_in, const int* in_sizes, int n_in,
                              void* d_out, int out_size, void* d_ws, size_t ws_size,
                              hipStream_t stream) {
    const float* cls  = (const float*)d_in[0];
    const float* reg  = (const float*)d_in[1];
    const float* anch = (const float*)d_in[2];
    const int* imh    = (const int*)d_in[3];
    const int* imw    = (const int*)d_in[4];
    int A = in_sizes[2] / 4;
    int Apad = (A + 255) & ~255;

    char* w = (char*)d_ws;
    size_t off = 0;
    auto alloc = [&](size_t bytes) -> void* {
        off = (off + 255) & ~(size_t)255;
        void* p = w + off;
        off += bytes;
        return p;
    };
    float*  candScore = (float*) alloc((size_t)C_NUM * TOPK * 4);
    float4* candBox   = (float4*)alloc((size_t)C_NUM * TOPK * 16);
    u64*    keepInit  = (u64*)   alloc((size_t)C_NUM * 16 * 8);
    u64*    keepFinal = (u64*)   alloc((size_t)C_NUM * 16 * 8);
    u64*    supW      = (u64*)   alloc((size_t)C_NUM * TOPK * 16 * 8);
    float*  scoresT   = (float*) alloc((size_t)C_NUM * Apad * 4);
    int useT = (off <= ws_size) ? 1 : 0;

    if (useT) {
        int nb = (A + 63) / 64;
        transpose_kernel<<<nb, 256, 0, stream>>>(cls, scoresT, A, Apad);
    }
    select_kernel<<<C_NUM, 1024, 0, stream>>>(cls, scoresT, useT, anch, reg, imh, imw,
                                              candScore, candBox, keepInit, A, Apad);
    iou_kernel<<<dim3(C_NUM, 5), 256, 0, stream>>>(candBox, supW);
    nms_seq_kernel<<<C_NUM, 64, 0, stream>>>(supW, keepInit, keepFinal);
    output_kernel<<<(C_NUM * TOPK + 255) / 256, 256, 0, stream>>>(candScore, candBox,
                                                                  keepFinal, (float*)d_out);
}